// Round 2
// baseline (19810.088 us; speedup 1.0000x reference)
//
#include <hip/hip_runtime.h>
#include <stdint.h>

typedef short          s16x8 __attribute__((ext_vector_type(8)));
typedef unsigned short u16x8 __attribute__((ext_vector_type(8)));
typedef unsigned short u16x4 __attribute__((ext_vector_type(4)));
typedef float          f32x4 __attribute__((ext_vector_type(4)));

#define L2E 1.44269504088896340736f

// ---- workspace layout (bytes) ----  total = 32 MB exactly
// (xg lives in d_out[0..16M floats) — stream-serialized: k_ingemm writes it,
//  k_lstm reads it, k_decgemm later overwrites that region with logits.)
#define WS_FLAGS   ((size_t)0)          // 4 * int
#define WS_HBUF    ((size_t)1024)       // 2 * 16 * 256 * 2 = 16 KB   (h hi/lo double buffer)
#define WS_WD16    ((size_t)65536)      // 10000*256*2 = 5,120,000    (w_dec bf16)
#define WS_H16     ((size_t)8388608)    // 2048*8*256*2 = 8 MB        (H, [s][b][d] bf16)
#define WS_HT16    ((size_t)16777216)   // 8*256*2048*2 = 8 MB        (H^T, [b][d][s] bf16)
#define WS_CTX16   ((size_t)25165824)   // 16384*256*2 = 8 MB         (attention output bf16)

#define OFF_HLAST  163840000
#define OFF_CLAST  163842048

static __device__ __forceinline__ unsigned short f2b(float f) {
  union { float f; uint32_t u; } v; v.f = f;
  uint32_t r = v.u + 0x7fffu + ((v.u >> 16) & 1u);   // round-to-nearest-even
  return (unsigned short)(r >> 16);
}
static __device__ __forceinline__ float b2f(unsigned short s) {
  union { uint32_t u; float f; } v; v.u = ((uint32_t)s) << 16;
  return v.f;
}
// XOR-swizzle: spread row-major rows across LDS banks (G4 fix)
static __device__ __forceinline__ uint32_t swz(uint32_t row, uint32_t byteInRow) {
  return byteInRow ^ ((row & 7u) << 4);
}
static __device__ __forceinline__ float sigm(float x) {
  return __builtin_amdgcn_rcpf(1.f + __builtin_amdgcn_exp2f(-L2E * x));
}
static __device__ __forceinline__ float th(float x) {
  return 2.f * __builtin_amdgcn_rcpf(1.f + __builtin_amdgcn_exp2f(-2.f * L2E * x)) - 1.f;
}

union PK { u16x8 u; s16x8 s; };

// ---------------- K0a: w_dec -> bf16 ----------------
__global__ void k_cvt_wdec(const float* __restrict__ wd, unsigned short* __restrict__ o16) {
  int i = blockIdx.x * 256 + threadIdx.x;            // 640000 float4s
  float4 v = ((const float4*)wd)[i];
  u16x4 r; r[0] = f2b(v.x); r[1] = f2b(v.y); r[2] = f2b(v.z); r[3] = f2b(v.w);
  *(u16x4*)(o16 + (size_t)i * 4) = r;
}

// ---------------- K0b: flags + h(0) hi/lo ----------------
__global__ void k_init(const float* __restrict__ h0, int* __restrict__ flags,
                       unsigned short* __restrict__ hbuf) {
  int t = threadIdx.x;                               // 256 threads
  if (t < 4) flags[t] = 0;
  for (int b = 0; b < 8; ++b) {
    float v = h0[b * 256 + t];
    unsigned short hi = f2b(v);
    hbuf[b * 256 + t]       = hi;                    // rows 0-7: hi
    hbuf[(b + 8) * 256 + t] = f2b(v - b2f(hi));      // rows 8-15: lo
  }
}

// ---------------- K2: Xg = emb_w[input] @ w_ih^T  (bf16 MFMA, fp32 out) ----------------
__global__ __launch_bounds__(512, 4) void k_ingemm(
    const int* __restrict__ inp, const float* __restrict__ emb,
    const float* __restrict__ wih, float* __restrict__ xg) {
  __shared__ __align__(16) char smA[32768];
  __shared__ __align__(16) char smB[32768];
  const int tid = threadIdx.x;
  const int n0 = blockIdx.x * 128, m0 = blockIdx.y * 128;
  const int w = tid >> 6, l = tid & 63;
  const int wr = w >> 2, wc = w & 3, lr = l & 15, lg = l >> 4;
  const int srow = tid >> 2, sli = tid & 3;
  const int token = inp[m0 + srow];
  const float* arow = emb + (size_t)token * 256;
  const float* brow = wih + (size_t)(n0 + srow) * 256;

  f32x4 acc[4][2];
#pragma unroll
  for (int mi = 0; mi < 4; ++mi)
#pragma unroll
    for (int ni = 0; ni < 2; ++ni) acc[mi][ni] = (f32x4){0.f, 0.f, 0.f, 0.f};

  for (int kh = 0; kh < 2; ++kh) {
#pragma unroll
    for (int i = 0; i < 4; ++i) {
      const int c = i * 4 + sli;                     // 16B chunk 0..15
      const int k = kh * 128 + c * 8;
      float4 a0 = *(const float4*)(arow + k);
      float4 a1 = *(const float4*)(arow + k + 4);
      PK pa;
      pa.u[0] = f2b(a0.x); pa.u[1] = f2b(a0.y); pa.u[2] = f2b(a0.z); pa.u[3] = f2b(a0.w);
      pa.u[4] = f2b(a1.x); pa.u[5] = f2b(a1.y); pa.u[6] = f2b(a1.z); pa.u[7] = f2b(a1.w);
      *(u16x8*)(smA + srow * 256 + swz(srow, c * 16)) = pa.u;
      float4 b0 = *(const float4*)(brow + k);
      float4 b1 = *(const float4*)(brow + k + 4);
      PK pb;
      pb.u[0] = f2b(b0.x); pb.u[1] = f2b(b0.y); pb.u[2] = f2b(b0.z); pb.u[3] = f2b(b0.w);
      pb.u[4] = f2b(b1.x); pb.u[5] = f2b(b1.y); pb.u[6] = f2b(b1.z); pb.u[7] = f2b(b1.w);
      *(u16x8*)(smB + srow * 256 + swz(srow, c * 16)) = pb.u;
    }
    __syncthreads();
#pragma unroll
    for (int kt = 0; kt < 4; ++kt) {
      s16x8 af[4], bf2[2];
#pragma unroll
      for (int mi = 0; mi < 4; ++mi) {
        const int row = (wr * 4 + mi) * 16 + lr;
        af[mi] = *(const s16x8*)(smA + row * 256 + swz(row, kt * 64 + lg * 16));
      }
#pragma unroll
      for (int ni = 0; ni < 2; ++ni) {
        const int row = (wc * 2 + ni) * 16 + lr;
        bf2[ni] = *(const s16x8*)(smB + row * 256 + swz(row, kt * 64 + lg * 16));
      }
#pragma unroll
      for (int mi = 0; mi < 4; ++mi)
#pragma unroll
        for (int ni = 0; ni < 2; ++ni)
          acc[mi][ni] = __builtin_amdgcn_mfma_f32_16x16x32_bf16(af[mi], bf2[ni], acc[mi][ni], 0, 0, 0);
    }
    __syncthreads();
  }
#pragma unroll
  for (int mi = 0; mi < 4; ++mi)
#pragma unroll
    for (int ni = 0; ni < 2; ++ni)
#pragma unroll
      for (int i = 0; i < 4; ++i) {
        const int r = m0 + (wr * 4 + mi) * 16 + lg * 4 + i;
        const int c = n0 + (wc * 2 + ni) * 16 + lr;
        xg[(size_t)r * 1024 + c] = acc[mi][ni][i];
      }
}

// ---------------- K3: LSTM scan, 4 persistent WGs, per-step spin sync ----------------
// WG g owns hidden units [g*64, g*64+64) => gate cols {q*256 + g*64 + 0..63, q=0..3}.
// Wave w (of 16): gate q = w>>2, unit chunk = w&3 (16 cols). W_hh frags live in VGPRs.
// MFMA M=16: rows 0-7 = h_hi (batch), rows 8-15 = h_lo  => fp32-precision h for free.
__global__ __launch_bounds__(1024, 4) void k_lstm(
    const float* __restrict__ c0, const float* __restrict__ whh,
    const float* __restrict__ xg, int* flags, unsigned short* hbuf,
    unsigned short* __restrict__ h16, unsigned short* __restrict__ ht16,
    float* __restrict__ dout) {
  __shared__ float gate_lds[4][8][64];
  __shared__ float c_lds[8][64];
  const int g = blockIdx.x;
  const int tid = threadIdx.x;
  const int w = tid >> 6, l = tid & 63;
  const int q = w >> 2, ch = w & 3;
  const int lr = l & 15, lg = l >> 4;
  const int col = q * 256 + g * 64 + ch * 16 + lr;   // gate col == w_hh row

  s16x8 wb[8];
#pragma unroll
  for (int kt = 0; kt < 8; ++kt) {                   // preload W_hh B-frags (bf16)
    const float* p = whh + (size_t)col * 256 + kt * 32 + lg * 8;
    float4 f0 = *(const float4*)p;
    float4 f1 = *(const float4*)(p + 4);
    PK pk;
    pk.u[0] = f2b(f0.x); pk.u[1] = f2b(f0.y); pk.u[2] = f2b(f0.z); pk.u[3] = f2b(f0.w);
    pk.u[4] = f2b(f1.x); pk.u[5] = f2b(f1.y); pk.u[6] = f2b(f1.z); pk.u[7] = f2b(f1.w);
    wb[kt] = pk.s;
  }
  if (tid < 512) {
    const int b = tid >> 6, j = tid & 63;
    c_lds[b][j] = c0[b * 256 + g * 64 + j];
  }
  __syncthreads();

  for (int t = 0; t < 2048; ++t) {
    // xg is step-constant: issue these global loads BEFORE the spin so the
    // (possible) L2/HBM miss latency hides under the flag wait.
    float xv[4];
    {
      const int rowx = (lg & 1) * 4;
#pragma unroll
      for (int i = 0; i < 4; ++i)
        xv[i] = xg[((size_t)t * 8 + rowx + i) * 1024 + col];
    }

    if (tid < 4) {                                   // wait for h(t) from all WGs
      while (__hip_atomic_load(&flags[tid], __ATOMIC_ACQUIRE, __HIP_MEMORY_SCOPE_AGENT) < t)
        __builtin_amdgcn_s_sleep(1);
    }
    __syncthreads();

    const char* hb = (const char*)hbuf + (size_t)(t & 1) * 8192 + (size_t)lr * 512 + lg * 16;
    s16x8 a[8];
#pragma unroll
    for (int kt = 0; kt < 8; ++kt) {                 // A-frags: h hi/lo, agent-scope loads
      const unsigned long long* p64 = (const unsigned long long*)(hb + kt * 64);
      union { unsigned long long u[2]; s16x8 s; } ua;
      ua.u[0] = __hip_atomic_load(p64,     __ATOMIC_RELAXED, __HIP_MEMORY_SCOPE_AGENT);
      ua.u[1] = __hip_atomic_load(p64 + 1, __ATOMIC_RELAXED, __HIP_MEMORY_SCOPE_AGENT);
      a[kt] = ua.s;
    }

    f32x4 acc = (f32x4){0.f, 0.f, 0.f, 0.f};
#pragma unroll
    for (int kt = 0; kt < 8; ++kt)
      acc = __builtin_amdgcn_mfma_f32_16x16x32_bf16(a[kt], wb[kt], acc, 0, 0, 0);

    float gv4[4];
#pragma unroll
    for (int i = 0; i < 4; ++i)                      // hi-rows + lo-rows (rows r and r+8)
      gv4[i] = acc[i] + __shfl_xor(acc[i], 32);

    if (l < 32) {
#pragma unroll
      for (int i = 0; i < 4; ++i)
        gate_lds[q][lg * 4 + i][ch * 16 + lr] = gv4[i] + xv[i];
    }
    __syncthreads();

    if (tid < 512) {
      const int b = tid >> 6, j = tid & 63;
      const float iv = gate_lds[0][b][j];
      const float fv = gate_lds[1][b][j];
      const float gg = gate_lds[2][b][j];
      const float ov = gate_lds[3][b][j];
      const float is = sigm(iv), fs = sigm(fv), os = sigm(ov);
      const float gs = th(gg);
      const float cn = fs * c_lds[b][j] + is * gs;
      c_lds[b][j] = cn;
      const float hn = os * th(cn);
      const unsigned short hi = f2b(hn);
      const unsigned short lo = f2b(hn - b2f(hi));
      const int unit = g * 64 + j;
      const int nb = (t + 1) & 1;
      __hip_atomic_store(&hbuf[nb * 4096 + b * 256 + unit], hi, __ATOMIC_RELAXED, __HIP_MEMORY_SCOPE_AGENT);
      __hip_atomic_store(&hbuf[nb * 4096 + (b + 8) * 256 + unit], lo, __ATOMIC_RELAXED, __HIP_MEMORY_SCOPE_AGENT);
      h16[((size_t)t * 8 + b) * 256 + unit] = hi;
      ht16[((size_t)b * 256 + unit) * 2048 + t] = hi;
      if (t == 2047) {
        dout[OFF_HLAST + b * 256 + unit] = hn;
        dout[OFF_CLAST + b * 256 + unit] = cn;
      }
    }
    __syncthreads();                                  // drains vmcnt for all waves
    if (tid == 0)
      __hip_atomic_store(&flags[g], t + 1, __ATOMIC_RELEASE, __HIP_MEMORY_SCOPE_AGENT);
  }
}

// ---------------- K4: causal flash attention, 1 block per (b, 64-row q-tile) ----------------
__global__ __launch_bounds__(256, 1) void k_attn(
    const unsigned short* __restrict__ h16, const unsigned short* __restrict__ ht16,
    unsigned short* __restrict__ ctx) {
  __shared__ __align__(16) char smem[65536];
  char* kb = smem;                                   // K tile [64][256] bf16 swizzled
  char* vb = smem + 32768;                           // V^T tile [256][64] bf16 swizzled
  const int bid = blockIdx.x;
  const int b = bid & 7, qt = bid >> 3;
  const int tid = threadIdx.x;
  const int w = tid >> 6, l = tid & 63, lr = l & 15, lg = l >> 4;

  s16x8 qf[8];                                       // Q A-frags in registers
  {
    const unsigned short* qp = h16 + ((size_t)(qt * 64 + w * 16 + lr) * 8 + b) * 256;
#pragma unroll
    for (int kt = 0; kt < 8; ++kt) qf[kt] = *(const s16x8*)(qp + kt * 32 + lg * 8);
  }
  f32x4 m_run = (f32x4){-3e38f, -3e38f, -3e38f, -3e38f};
  f32x4 l_run = (f32x4){0.f, 0.f, 0.f, 0.f};
  f32x4 o[16];
#pragma unroll
  for (int n = 0; n < 16; ++n) o[n] = (f32x4){0.f, 0.f, 0.f, 0.f};

  for (int kt2 = 0; kt2 <= qt; ++kt2) {
    __syncthreads();
    {                                                // stage K
      const int row = tid >> 2, li = tid & 3;
      const unsigned short* src = h16 + ((size_t)(kt2 * 64 + row) * 8 + b) * 256;
      char* dst = kb + row * 512;
#pragma unroll
      for (int i = 0; i < 8; ++i) {
        const int c = i * 4 + li;
        u16x8 v = *(const u16x8*)(src + c * 8);
        *(u16x8*)(dst + swz(row, c * 16)) = v;
      }
    }
    {                                                // stage V^T
      const int grp = tid >> 3, li = tid & 7;
#pragma unroll
      for (int r = 0; r < 8; ++r) {
        const int d = grp * 8 + r;
        u16x8 v = *(const u16x8*)(ht16 + ((size_t)b * 256 + d) * 2048 + kt2 * 64 + li * 8);
        *(u16x8*)(vb + d * 128 + swz(d, li * 16)) = v;
      }
    }
    __syncthreads();

    f32x4 s[4];
#pragma unroll
    for (int n = 0; n < 4; ++n) s[n] = (f32x4){0.f, 0.f, 0.f, 0.f};
#pragma unroll
    for (int kt = 0; kt < 8; ++kt) {
#pragma unroll
      for (int n = 0; n < 4; ++n) {
        const int row = n * 16 + lr;
        s16x8 kf = *(const s16x8*)(kb + row * 512 + swz(row, kt * 64 + lg * 16));
        s[n] = __builtin_amdgcn_mfma_f32_16x16x32_bf16(qf[kt], kf, s[n], 0, 0, 0);
      }
    }
    if (kt2 == qt) {                                 // causal mask on diagonal tile
#pragma unroll
      for (int n = 0; n < 4; ++n)
#pragma unroll
        for (int i = 0; i < 4; ++i) {
          const int kv = kt2 * 64 + n * 16 + lr;
          const int qg = qt * 64 + w * 16 + lg * 4 + i;
          if (kv > qg) s[n][i] = -3e38f;
        }
    }
    f32x4 mx;
#pragma unroll
    for (int i = 0; i < 4; ++i)
      mx[i] = fmaxf(fmaxf(s[0][i], s[1][i]), fmaxf(s[2][i], s[3][i]));
#pragma unroll
    for (int off = 1; off < 16; off <<= 1)
#pragma unroll
      for (int i = 0; i < 4; ++i) mx[i] = fmaxf(mx[i], __shfl_xor(mx[i], off));
    f32x4 mnew, scl, rsum;
#pragma unroll
    for (int i = 0; i < 4; ++i) {
      mnew[i] = fmaxf(m_run[i], mx[i]);
      scl[i] = __builtin_amdgcn_exp2f((m_run[i] - mnew[i]) * L2E);
      rsum[i] = 0.f;
    }
#pragma unroll
    for (int n = 0; n < 4; ++n)
#pragma unroll
      for (int i = 0; i < 4; ++i) {
        const float p = __builtin_amdgcn_exp2f((s[n][i] - mnew[i]) * L2E);
        s[n][i] = p;
        rsum[i] += p;
      }
#pragma unroll
    for (int off = 1; off < 16; off <<= 1)
#pragma unroll
      for (int i = 0; i < 4; ++i) rsum[i] += __shfl_xor(rsum[i], off);
#pragma unroll
    for (int i = 0; i < 4; ++i) {
      l_run[i] = l_run[i] * scl[i] + rsum[i];
      m_run[i] = mnew[i];
    }
#pragma unroll
    for (int n = 0; n < 16; ++n)
#pragma unroll
      for (int i = 0; i < 4; ++i) o[n][i] *= scl[i];

    __syncthreads();                                 // everyone done reading K
    {                                                // P -> LDS (per-wave region aliases kb)
      char* pb = smem + w * 2048;
#pragma unroll
      for (int n = 0; n < 4; ++n)
#pragma unroll
        for (int i = 0; i < 4; ++i) {
          const int row = lg * 4 + i;
          *(unsigned short*)(pb + row * 128 + swz(row, (n * 16 + lr) * 2)) = f2b(s[n][i]);
        }
    }
#pragma unroll
    for (int kp = 0; kp < 2; ++kp) {                 // PV
      const char* pb = smem + w * 2048;
      s16x8 pf = *(const s16x8*)(pb + lr * 128 + swz(lr, kp * 64 + lg * 16));
#pragma unroll
      for (int n = 0; n < 16; ++n) {
        const int d = n * 16 + lr;
        s16x8 vf = *(const s16x8*)(vb + d * 128 + swz(d, kp * 64 + lg * 16));
        o[n] = __builtin_amdgcn_mfma_f32_16x16x32_bf16(pf, vf, o[n], 0, 0, 0);
      }
    }
  }
  f32x4 rl;
#pragma unroll
  for (int i = 0; i < 4; ++i) rl[i] = __builtin_amdgcn_rcpf(l_run[i]);
#pragma unroll
  for (int n = 0; n < 16; ++n)
#pragma unroll
    for (int i = 0; i < 4; ++i) {
      const int qg = qt * 64 + w * 16 + lg * 4 + i;
      ctx[((size_t)qg * 8 + b) * 256 + n * 16 + lr] = f2b(o[n][i] * rl[i]);
    }
}

// ---------------- K5: logits = ctx @ w_dec^T + b_dec -> d_out (fp32) ----------------
__global__ __launch_bounds__(512, 4) void k_decgemm(
    const unsigned short* __restrict__ ctx, const unsigned short* __restrict__ wd16,
    const float* __restrict__ bdec, float* __restrict__ out) {
  __shared__ __align__(16) char smA[32768];
  __shared__ __align__(16) char smB[32768];
  const int tid = threadIdx.x;
  const int n0 = blockIdx.x * 128, m0 = blockIdx.y * 128;
  const int w = tid >> 6, l = tid & 63;
  const int wr = w >> 2, wc = w & 3, lr = l & 15, lg = l >> 4;
  const int srow = tid >> 2, sli = tid & 3;
  const int grow = n0 + srow;
  const unsigned short* arow = ctx + (size_t)(m0 + srow) * 256;
  const unsigned short* brow = wd16 + (size_t)grow * 256;

  f32x4 acc[4][2];
#pragma unroll
  for (int mi = 0; mi < 4; ++mi)
#pragma unroll
    for (int ni = 0; ni < 2; ++ni) acc[mi][ni] = (f32x4){0.f, 0.f, 0.f, 0.f};

  for (int kh = 0; kh < 2; ++kh) {
#pragma unroll
    for (int i = 0; i < 4; ++i) {
      const int c = i * 4 + sli;
      const int k = kh * 128 + c * 8;
      u16x8 va = *(const u16x8*)(arow + k);
      *(u16x8*)(smA + srow * 256 + swz(srow, c * 16)) = va;
      u16x8 vbv;
      if (grow < 10000) vbv = *(const u16x8*)(brow + k);
      else vbv = (u16x8){0, 0, 0, 0, 0, 0, 0, 0};
      *(u16x8*)(smB + srow * 256 + swz(srow, c * 16)) = vbv;
    }
    __syncthreads();
#pragma unroll
    for (int kt = 0; kt < 4; ++kt) {
      s16x8 af[4], bf2[2];
#pragma unroll
      for (int mi = 0; mi < 4; ++mi) {
        const int row = (wr * 4 + mi) * 16 + lr;
        af[mi] = *(const s16x8*)(smA + row * 256 + swz(row, kt * 64 + lg * 16));
      }
#pragma unroll
      for (int ni = 0; ni < 2; ++ni) {
        const int row = (wc * 2 + ni) * 16 + lr;
        bf2[ni] = *(const s16x8*)(smB + row * 256 + swz(row, kt * 64 + lg * 16));
      }
#pragma unroll
      for (int mi = 0; mi < 4; ++mi)
#pragma unroll
        for (int ni = 0; ni < 2; ++ni)
          acc[mi][ni] = __builtin_amdgcn_mfma_f32_16x16x32_bf16(af[mi], bf2[ni], acc[mi][ni], 0, 0, 0);
    }
    __syncthreads();
  }
#pragma unroll
  for (int mi = 0; mi < 4; ++mi)
#pragma unroll
    for (int ni = 0; ni < 2; ++ni)
#pragma unroll
      for (int i = 0; i < 4; ++i) {
        const int c = n0 + (wc * 2 + ni) * 16 + lr;
        if (c < 10000) {
          const int r = m0 + (wr * 4 + mi) * 16 + lg * 4 + i;
          out[(size_t)r * 10000 + c] = acc[mi][ni][i] + bdec[c];
        }
      }
}

// ---------------- K6: in-place log_softmax over each row of 10000 ----------------
__global__ __launch_bounds__(256, 4) void k_lsm(float* __restrict__ out) {
  __shared__ float red[8];
  const int tid = threadIdx.x;
  float* p = out + (size_t)blockIdx.x * 10000;
  float4 v[10];
  float m = -3e38f;
#pragma unroll
  for (int it = 0; it < 10; ++it) {
    const int idx = tid + it * 256;
    if (idx < 2500) {
      v[it] = *((const float4*)p + idx);
      m = fmaxf(m, fmaxf(fmaxf(v[it].x, v[it].y), fmaxf(v[it].z, v[it].w)));
    }
  }
#pragma unroll
  for (int off = 1; off < 64; off <<= 1) m = fmaxf(m, __shfl_xor(m, off));
  if ((tid & 63) == 0) red[tid >> 6] = m;
  __syncthreads();
  m = fmaxf(fmaxf(red[0], red[1]), fmaxf(red[2], red[3]));
  float sum = 0.f;
#pragma unroll
  for (int it = 0; it < 10; ++it) {
    const int idx = tid + it * 256;
    if (idx < 2500) {
      sum += __builtin_amdgcn_exp2f((v[it].x - m) * L2E);
      sum += __builtin_amdgcn_exp2f((v[it].y - m) * L2E);
      sum += __builtin_amdgcn_exp2f((v[it].z - m) * L2E);
      sum += __builtin_amdgcn_exp2f((v[it].w - m) * L2E);
    }
  }
#pragma unroll
  for (int off = 1; off < 64; off <<= 1) sum += __shfl_xor(sum, off);
  if ((tid & 63) == 0) red[4 + (tid >> 6)] = sum;
  __syncthreads();
  sum = red[4] + red[5] + red[6] + red[7];
  const float lse = m + 0.6931471805599453f * __builtin_amdgcn_logf(sum);
#pragma unroll
  for (int it = 0; it < 10; ++it) {
    const int idx = tid + it * 256;
    if (idx < 2500) {
      float4 r = v[it];
      r.x -= lse; r.y -= lse; r.z -= lse; r.w -= lse;
      *((float4*)p + idx) = r;
    }
  }
}

extern "C" void kernel_launch(void* const* d_in, const int* in_sizes, int n_in,
                              void* d_out, int out_size, void* d_ws, size_t ws_size,
                              hipStream_t stream) {
  (void)in_sizes; (void)n_in; (void)out_size; (void)ws_size;
  const int*   inp  = (const int*)d_in[0];
  const float* h0   = (const float*)d_in[1];
  const float* c0   = (const float*)d_in[2];
  const float* emb  = (const float*)d_in[3];
  const float* wih  = (const float*)d_in[4];
  const float* whh  = (const float*)d_in[5];
  const float* wdec = (const float*)d_in[6];
  const float* bdec = (const float*)d_in[7];
  float* out = (float*)d_out;
  char* ws = (char*)d_ws;
  int* flags            = (int*)(ws + WS_FLAGS);
  unsigned short* hbuf  = (unsigned short*)(ws + WS_HBUF);
  unsigned short* wd16  = (unsigned short*)(ws + WS_WD16);
  unsigned short* h16   = (unsigned short*)(ws + WS_H16);
  unsigned short* ht16  = (unsigned short*)(ws + WS_HT16);
  unsigned short* ctx16 = (unsigned short*)(ws + WS_CTX16);
  float* xg             = out;                       // borrow d_out: overwritten by k_decgemm later

  k_cvt_wdec<<<dim3(2500), dim3(256), 0, stream>>>(wdec, wd16);
  k_init<<<dim3(1), dim3(256), 0, stream>>>(h0, flags, hbuf);
  k_ingemm<<<dim3(8, 128), dim3(512), 0, stream>>>(inp, emb, wih, xg);
  k_lstm<<<dim3(4), dim3(1024), 0, stream>>>(c0, whh, xg, flags, hbuf, h16, ht16, out);
  k_attn<<<dim3(256), dim3(256), 0, stream>>>(h16, ht16, ctx16);
  k_decgemm<<<dim3(79, 128), dim3(512), 0, stream>>>(ctx16, wd16, bdec, out);
  k_lsm<<<dim3(16384), dim3(256), 0, stream>>>(out);
}